// Round 5
// baseline (129.851 us; speedup 1.0000x reference)
//
#include <hip/hip_runtime.h>

// SimpleRelativeAttention collapses twice:
// 1. einsum 'bnqk,bnqe->bnqe' multiplies v by softmax row-sums (==1) -> attention
//    is an identity on v. rel_table/rel_index/q/k are dead.
// 2. out = x @ Wv @ Wproj + (b_v @ Wproj + b_proj); fold W_c = Wv @ Wproj
//    (1024^3 mini-GEMM) so the hot path is ONE 4096x1024x1024 GEMM.
// Timed window carries ~88us of harness poison/restore (fillBufferAligned
// 268MB @ ~43us each, in-window per timestamps). Controllable budget ~40us;
// this round: 3 dispatches total (mega-prep / gemm1+cast / main GEMM BK=128).

#define DIMC 1024
#define MTOT 4096   // BATCH * SEQ

__device__ __forceinline__ unsigned short f2bf(float f) {
  unsigned u = __float_as_uint(f);
  u += 0x7FFFu + ((u >> 16) & 1u);   // round-to-nearest-even
  return (unsigned short)(u >> 16);
}

typedef __attribute__((ext_vector_type(8))) short short8;
typedef __attribute__((ext_vector_type(4))) float floatx4;

__device__ __forceinline__ void async_copy16(const unsigned short* g, unsigned short* l) {
  __builtin_amdgcn_global_load_lds(
      (const __attribute__((address_space(1))) unsigned int*)g,
      (__attribute__((address_space(3))) unsigned int*)l,
      16, 0, 0);
}

// D1: mega-prep, grid 1056.
// Blocks [0,1024): (bx=b&31, by=b>>5)
//   WpT[n][j] = w_proj[j][n]           (32x32 LDS transpose + cast)
//   Wvb[k][j] = w_qkv[k][2048+j]       (straight cast)
// Blocks [1024,1056): b_c[n] = sum_j b_v[j]*w_proj[j][n]  (no atomics)
__global__ void prep_kernel(const float* __restrict__ w_proj,
                            const float* __restrict__ w_qkv,
                            const float* __restrict__ b_v,
                            unsigned short* __restrict__ WpT,
                            unsigned short* __restrict__ Wvb,
                            float* __restrict__ b_c) {
  const int b = blockIdx.x;
  const int t = threadIdx.x;
  if (b < 1024) {
    __shared__ float tile[32][33];
    const int bx = b & 31, by = b >> 5;
    const int tx = t & 31, ty = t >> 5;
#pragma unroll
    for (int r = 0; r < 4; ++r) {
      int kl = ty + r * 8;
      tile[kl][tx] = w_proj[(size_t)(by * 32 + kl) * DIMC + bx * 32 + tx];
    }
    {  // w_qkv slice cast (independent of LDS)
      const int r2 = t >> 3, c4 = (t & 7) * 4;
      float4 f = *(const float4*)(w_qkv + (size_t)(by * 32 + r2) * (3 * DIMC) +
                                  2 * DIMC + bx * 32 + c4);
      ushort4 o;
      o.x = f2bf(f.x); o.y = f2bf(f.y); o.z = f2bf(f.z); o.w = f2bf(f.w);
      *(ushort4*)(Wvb + (size_t)(by * 32 + r2) * DIMC + bx * 32 + c4) = o;
    }
    __syncthreads();
#pragma unroll
    for (int r = 0; r < 4; ++r) {
      int nl = ty + r * 8;
      WpT[(size_t)(bx * 32 + nl) * DIMC + by * 32 + tx] = f2bf(tile[tx][nl]);
    }
  } else {
    __shared__ float red[256];
    const int bb = b - 1024;
    const int n = bb * 32 + (t & 31);
    const int jc = t >> 5;                    // 8 j-chunks of 128
    float s = 0.f;
    for (int j = jc * 128; j < jc * 128 + 128; ++j)
      s += b_v[j] * w_proj[(size_t)j * DIMC + n];
    red[t] = s;
    __syncthreads();
    if (t < 32) {
      float a = 0.f;
#pragma unroll
      for (int c = 0; c < 8; ++c) a += red[c * 32 + t];
      b_c[n] = a;
    }
  }
}

// Generic BT GEMM body: C[M,N] = A[M,K] @ Bt[N,K]^T (+ bias + bias2).
// BMxBN block tile, BK k-tile, 256 thr = 4 waves in 2x2, 16x16x32 bf16 MFMA.
// global_load_lds width-16 staging; bank conflicts broken by a global-side
// XOR swizzle: physical slot p of LDS row r holds global k-chunk p^(r&(W-1)),
// W = BK/8 chunks per row. Staging stays coalesced (permutation within a
// 2*BK-byte row segment); ds_read_b128 fragment reads hit 2-way aliasing only.
template <int BM, int BN, int BK, int K, bool BF16_OUT, bool SWZ>
__device__ __forceinline__ void gemm_body(
    const unsigned short* __restrict__ A, const unsigned short* __restrict__ Bt,
    const float* __restrict__ bias, const float* __restrict__ bias2,
    void* __restrict__ Cout, int N, int bid,
    unsigned short* As, unsigned short* Bs) {
  constexpr int W  = BK / 8;           // k-chunks per LDS row
  constexpr int MI = BM / 32, NI = BN / 32;
  constexpr int AG = BM * BK / 2048;   // staging glls/thread for A
  constexpr int BG = BN * BK / 2048;
  constexpr int NS = BK / 32;          // mfma k-steps per tile
  constexpr int RG = 256 / W;          // rows staged per g-step

  const int tid = threadIdx.x;
  const int wv = tid >> 6, lane = tid & 63;

  int bx, by;
  if (SWZ) {  // 256 blocks: xcd=bid&7 -> 4 row-tiles x all col-tiles in its L2
    bx = (bid >> 3) & 7;
    by = (bid & 7) * 4 + (bid >> 6);
  } else {
    bx = bid % (DIMC / BN);
    by = bid / (DIMC / BN);
  }
  const int m0 = by * BM, n0 = bx * BN;

  floatx4 acc[MI][NI] = {};

  // staging: chunk c = g*256 + tid -> (row = c/W, slot = c%W = tid%W);
  // global k-chunk for slot p of row r is p^(r&(W-1)); row%W == SR%W for all g.
  const int SR = tid / W;
  const int skc = (tid & (W - 1)) ^ (SR & (W - 1));
  const unsigned short* Ab = A + (size_t)(m0 + SR) * K + skc * 8;
  const unsigned short* Bb = Bt + (size_t)(n0 + SR) * K + skc * 8;

  const int lr = lane & 15, qr = lane >> 4;
  const int fr = lr & (W - 1);         // fragment-read swizzle key (= row%W)
  const int wrow = (wv >> 1) * (BM / 2), wcol = (wv & 1) * (BN / 2);

  for (int k0 = 0; k0 < K; k0 += BK) {
#pragma unroll
    for (int g = 0; g < AG; ++g)
      async_copy16(Ab + (size_t)g * RG * K + k0, As + (g * 256 + wv * 64) * 8);
#pragma unroll
    for (int g = 0; g < BG; ++g)
      async_copy16(Bb + (size_t)g * RG * K + k0, Bs + (g * 256 + wv * 64) * 8);
    __syncthreads();   // drains vmcnt before barrier

#pragma unroll
    for (int s = 0; s < NS; ++s) {
      short8 a[MI], b[NI];
      const int kph = ((s * 4 + qr) ^ fr) * 8;
#pragma unroll
      for (int mi = 0; mi < MI; ++mi)
        a[mi] = *(const short8*)(As + (wrow + mi * 16 + lr) * BK + kph);
#pragma unroll
      for (int ni = 0; ni < NI; ++ni)
        b[ni] = *(const short8*)(Bs + (wcol + ni * 16 + lr) * BK + kph);
#pragma unroll
      for (int mi = 0; mi < MI; ++mi)
#pragma unroll
        for (int ni = 0; ni < NI; ++ni)
          acc[mi][ni] = __builtin_amdgcn_mfma_f32_16x16x32_bf16(a[mi], b[ni],
                                                                acc[mi][ni], 0, 0, 0);
    }
    __syncthreads();
  }

  // epilogue: C row = m0+wrow+mi*16+qr*4+r, col = n0+wcol+ni*16+lr
#pragma unroll
  for (int mi = 0; mi < MI; ++mi) {
#pragma unroll
    for (int ni = 0; ni < NI; ++ni) {
      const int col = n0 + wcol + ni * 16 + lr;
      float bv = 0.0f;
      if (bias)  bv += bias[col];
      if (bias2) bv += bias2[col];
#pragma unroll
      for (int r = 0; r < 4; ++r) {
        const int row = m0 + wrow + mi * 16 + qr * 4 + r;
        const float val = acc[mi][ni][r] + bv;
        if (BF16_OUT)
          ((unsigned short*)Cout)[(size_t)row * N + col] = f2bf(val);
        else
          ((float*)Cout)[(size_t)row * N + col] = val;
      }
    }
  }
}

// D2: blocks [0,256) = gemm1 (WcT = (Wv@Wproj)^T, 64x64 tiles);
//     blocks [256,2304) = x fp32->bf16 cast (8 elems/thread) — overlaps
//     gemm1's compute with the cast's bandwidth on other CUs.
__global__ __launch_bounds__(256, 2) void d2_kernel(
    const unsigned short* __restrict__ WpT, const unsigned short* __restrict__ Wvb,
    unsigned short* __restrict__ WcT,
    const float* __restrict__ x, unsigned short* __restrict__ xb) {
  if (blockIdx.x < 256) {
    __shared__ __align__(16) unsigned short As[64 * 64];
    __shared__ __align__(16) unsigned short Bs[64 * 64];
    gemm_body<64, 64, 64, DIMC, true, false>(WpT, Wvb, nullptr, nullptr, WcT,
                                             DIMC, blockIdx.x, As, Bs);
  } else {
    const int b = blockIdx.x - 256;
    const int i = (b * 256 + threadIdx.x) * 8;
    float4 f0 = *(const float4*)(x + i);
    float4 f1 = *(const float4*)(x + i + 4);
    ushort4 o0, o1;
    o0.x = f2bf(f0.x); o0.y = f2bf(f0.y); o0.z = f2bf(f0.z); o0.w = f2bf(f0.w);
    o1.x = f2bf(f1.x); o1.y = f2bf(f1.y); o1.z = f2bf(f1.z); o1.w = f2bf(f1.w);
    *(ushort4*)(xb + i) = o0;
    *(ushort4*)(xb + i + 4) = o1;
  }
}

// D3: out = xb @ WcT^T + (b_c + b_proj). 128x128 tile, BK=128 (64KB LDS; grid
// is 256 = 1 block/CU anyway, so big LDS costs nothing and halves barriers).
__global__ __launch_bounds__(256, 2) void gemm_main_kernel(
    const unsigned short* __restrict__ A, const unsigned short* __restrict__ Bt,
    const float* __restrict__ bias, const float* __restrict__ bias2,
    float* __restrict__ C) {
  __shared__ __align__(16) unsigned short As[128 * 128];
  __shared__ __align__(16) unsigned short Bs[128 * 128];
  gemm_body<128, 128, 128, DIMC, false, true>(A, Bt, bias, bias2, C,
                                              DIMC, blockIdx.x, As, Bs);
}

extern "C" void kernel_launch(void* const* d_in, const int* in_sizes, int n_in,
                              void* d_out, int out_size, void* d_ws, size_t ws_size,
                              hipStream_t stream) {
  const float* x      = (const float*)d_in[0];  // [4,1024,1024]
  const float* w_qkv  = (const float*)d_in[1];  // [1024,3072]
  const float* b_qkv  = (const float*)d_in[2];  // [3072]
  const float* w_proj = (const float*)d_in[3];  // [1024,1024]
  const float* b_proj = (const float*)d_in[4];  // [1024]
  // d_in[5]=rel_table, d_in[6]=rel_index unused (softmax rows sum to 1).
  float* out = (float*)d_out;

  char* ws = (char*)d_ws;
  unsigned short* xb  = (unsigned short*)(ws);                       // 8 MB [4096,1024]
  unsigned short* WpT = (unsigned short*)(ws + (size_t)(8u << 20));  // 2 MB WpT[n][j]=w_proj[j][n]
  unsigned short* Wvb = (unsigned short*)(ws + (size_t)(10u << 20)); // 2 MB Wvb[k][j]=w_qkv[k][2048+j]
  unsigned short* WcT = (unsigned short*)(ws + (size_t)(12u << 20)); // 2 MB WcT[n][k]=W_c[k][n]
  float*          b_c = (float*)(ws + (size_t)(14u << 20));          // 4 KB

  // D1: weight transpose/cast + bias matvec (1024 + 32 blocks)
  prep_kernel<<<1056, 256, 0, stream>>>(w_proj, w_qkv, b_qkv + 2 * DIMC,
                                        WpT, Wvb, b_c);
  // D2: gemm1 (256 blocks) + x cast (2048 blocks)
  d2_kernel<<<2304, 256, 0, stream>>>(WpT, Wvb, WcT, x, xb);
  // D3: main GEMM (256 blocks, XCD swizzle)
  gemm_main_kernel<<<256, 256, 0, stream>>>(xb, WcT, b_c, b_proj, out);
}